// Round 6
// baseline (75.062 us; speedup 1.0000x reference)
//
#include <hip/hip_runtime.h>

#define NB 16
#define NC 7
#define NK 6
#define HC 160
#define WC 160
#define HF 640
#define WF 640
#define NCOARSE (HC*WC)             // 25600 coarse pixels per batch
#define NFINE   (HF*WF)             // 409600 fine pixels per batch
#define BLOCKS_PER_B (NCOARSE/256)  // 100
#define NACC 27
#define ACC_STRIDE 32
#define EPSF 1e-6f

// ---------------- ws layout (bytes) ----------------
// acc      float[16*32]   @ 0        (2048)  [zeroed]
// pos_num  int[16]        @ 2048             [zeroed]
// neg_tot  int[16]        @ 2112             [zeroed]
// v1s      int[16]        @ 2176
// k2s      int[16]        @ 2240
// v2s      int[16]        @ 2304
// k3s      int[16]        @ 2368
// flb      int[16]        @ 2432             [always written by B2]
// hist1    int[16][2048]  @ 4096    (131072) [zeroed]
// hist2    int[16][2048]  @ 135168  (131072) [zeroed]
// hist3    int[16][1024]  @ 266240  (65536)  [zeroed]
// bits     uint[409600]   @ 331776 (1638400) [written by A]
#define WS_POS   2048
#define WS_NEG   2112
#define WS_V1    2176
#define WS_K2    2240
#define WS_V2    2304
#define WS_K3    2368
#define WS_FLB   2432
#define WS_H1    4096
#define WS_H2    135168
#define WS_H3    266240
#define WS_BITS  331776
#define WS_ZERO_BYTES 331776   // = 20736 uint4 = 81*256

__device__ __forceinline__ unsigned score_key(float s) {
    unsigned u = __float_as_uint(s);
    return (u & 0x80000000u) ? ~u : (u | 0x80000000u);
}

// ---------- init: zero acc + counters + hist1/2/3 ----------
__global__ __launch_bounds__(256) void psel_init(uint4* __restrict__ ws4) {
    int i = blockIdx.x * 256 + threadIdx.x;
    ws4[i] = uint4{0u, 0u, 0u, 0u};   // grid sized exactly to WS_ZERO_BYTES/16
}

// Parallel weighted descending select over a global histogram (256-thread block).
// Finds bin v = first (from top bin downward) where cumulative weight >= k;
// krem = k - (weight strictly above v). Block-uniform; all threads must call.
template<int NBINS>
__device__ __forceinline__ int bsel256(const int* __restrict__ gh, int k, int& krem)
{
    constexpr int CH = NBINS / 256;
    __shared__ int lh[NBINS];
    __shared__ int wt4[4];
    __shared__ int wsuf[5];
    __shared__ int res[2];
    int t = threadIdx.x, wid = t >> 6, lane = t & 63;
    #pragma unroll
    for (int i = 0; i < CH; ++i) lh[t + 256*i] = gh[t + 256*i];
    __syncthreads();
    int c = 0;
    #pragma unroll
    for (int j = 0; j < CH; ++j) c += lh[t*CH + j];
    int s = c;                          // wave suffix-sum of chunk totals
    #pragma unroll
    for (int off = 1; off < 64; off <<= 1) {
        int v = __shfl_down(s, off);
        if (lane + off < 64) s += v;
    }
    if (lane == 0) wt4[wid] = s;
    __syncthreads();
    if (t < 4) { int sum = 0; for (int j = t; j < 4; ++j) sum += wt4[j]; wsuf[t] = sum; }
    if (t == 0) { wsuf[4] = 0; res[0] = 0; res[1] = k; }
    __syncthreads();
    int G = s + wsuf[wid + 1];          // weight from this thread's chunk to top
    int above = G - c;                  // weight strictly above this chunk
    if (G >= k && above < k) {          // unique straddling thread
        int cum = above;
        for (int u = t*CH + CH - 1; u >= t*CH; --u) {
            cum += lh[u];
            if (cum >= k) { res[0] = u; res[1] = k - (cum - lh[u]); break; }
        }
    }
    __syncthreads();
    krem = res[1];
    return res[0];
}

// ---------- Phase A: bits + pos/neg counts + level-1 weighted histogram ----------
__global__ __launch_bounds__(256) void psel_phaseA(
    const float* __restrict__ maps, const float* __restrict__ gt,
    const float* __restrict__ tm, int* __restrict__ pos_num,
    int* __restrict__ neg_tot, int* __restrict__ hist1,
    unsigned* __restrict__ bitsbuf)
{
    __shared__ int lh[2048];
    __shared__ int sp[4], sn[4];
    int t = threadIdx.x;
    #pragma unroll
    for (int i = 0; i < 8; ++i) lh[t + 256*i] = 0;

    int bid = blockIdx.x;
    int b = bid / BLOCKS_PER_B;
    int r = (bid % BLOCKS_PER_B) * 256 + t;
    int cy = r / WC, cx = r % WC;
    const float* gtb = gt + (size_t)b * NFINE;
    const float* tmb = tm + (size_t)b * NFINE;
    unsigned gb = 0, mb = 0;
    #pragma unroll
    for (int row = 0; row < 4; ++row) {
        int off = (cy*4 + row)*WF + cx*4;
        float4 g4 = *reinterpret_cast<const float4*>(gtb + off);
        float4 m4 = *reinterpret_cast<const float4*>(tmb + off);
        unsigned sh = 4*row;
        gb |= ((g4.x > 0.5f) ? 1u : 0u) << (sh+0);
        gb |= ((g4.y > 0.5f) ? 1u : 0u) << (sh+1);
        gb |= ((g4.z > 0.5f) ? 1u : 0u) << (sh+2);
        gb |= ((g4.w > 0.5f) ? 1u : 0u) << (sh+3);
        mb |= ((m4.x > 0.5f) ? 1u : 0u) << (sh+0);
        mb |= ((m4.y > 0.5f) ? 1u : 0u) << (sh+1);
        mb |= ((m4.z > 0.5f) ? 1u : 0u) << (sh+2);
        mb |= ((m4.w > 0.5f) ? 1u : 0u) << (sh+3);
    }
    bitsbuf[b*NCOARSE + r] = (mb << 16) | gb;
    int posc = __popc(gb & mb);
    int negc = 16 - __popc(gb);

    unsigned key = score_key(maps[(size_t)b * NC * NCOARSE + r]);  // channel 0
    __syncthreads();
    if (negc) atomicAdd(&lh[key >> 21], negc);

    #pragma unroll
    for (int off = 32; off; off >>= 1) {
        posc += __shfl_down(posc, off);
        negc += __shfl_down(negc, off);
    }
    int wid = t >> 6, lane = t & 63;
    if (lane == 0) { sp[wid] = posc; sn[wid] = negc; }
    __syncthreads();   // also orders all lh atomics before the flush below
    if (t == 0) {
        atomicAdd(&pos_num[b], sp[0]+sp[1]+sp[2]+sp[3]);
        atomicAdd(&neg_tot[b], sn[0]+sn[1]+sn[2]+sn[3]);
    }
    int* gh = hist1 + b*2048;
    #pragma unroll
    for (int i = 0; i < 8; ++i) {
        int v = lh[t + 256*i];
        if (v) atomicAdd(&gh[t + 256*i], v);
    }
}

// ---------- Phase B2: parallel scan of hist1 + build hist2 ----------
__global__ __launch_bounds__(256) void psel_phaseB2(
    const float* __restrict__ maps, const unsigned* __restrict__ bitsbuf,
    const int* __restrict__ pos_num, const int* __restrict__ neg_tot,
    const int* __restrict__ hist1, int* __restrict__ hist2,
    int* __restrict__ v1s, int* __restrict__ k2s, int* __restrict__ flb)
{
    int bid = blockIdx.x;
    int b = bid / BLOCKS_PER_B;
    bool desig = (bid % BLOCKS_PER_B) == 0;
    int pos = pos_num[b];
    long long negT = neg_tot[b];
    long long nn = (long long)pos * 3; if (nn > negT) nn = negT;
    int k = (int)nn;
    if (pos == 0 || k == 0) {
        if (desig && threadIdx.x == 0) flb[b] = 1;
        return;
    }
    int k2;
    int v1 = bsel256<2048>(hist1 + b*2048, k, k2);
    if (desig && threadIdx.x == 0) { v1s[b] = v1; k2s[b] = k2; flb[b] = 0; }

    int r = (bid % BLOCKS_PER_B) * 256 + threadIdx.x;
    unsigned key = score_key(maps[(size_t)b * NC * NCOARSE + r]);
    if ((int)(key >> 21) == v1) {
        int w = 16 - __popc(bitsbuf[b*NCOARSE + r] & 0xFFFFu);
        if (w) atomicAdd(&hist2[b*2048 + (int)((key >> 10) & 2047u)], w);
    }
}

// ---------- Phase B4: parallel scan of hist2 + build hist3 ----------
__global__ __launch_bounds__(256) void psel_phaseB4(
    const float* __restrict__ maps, const unsigned* __restrict__ bitsbuf,
    const int* __restrict__ hist2, int* __restrict__ hist3,
    const int* __restrict__ v1s, const int* __restrict__ k2s,
    int* __restrict__ v2s, int* __restrict__ k3s, const int* __restrict__ flb)
{
    int bid = blockIdx.x;
    int b = bid / BLOCKS_PER_B;
    if (flb[b]) return;
    bool desig = (bid % BLOCKS_PER_B) == 0;
    int v1 = v1s[b];
    int k3;
    int v2 = bsel256<2048>(hist2 + b*2048, k2s[b], k3);
    if (desig && threadIdx.x == 0) { v2s[b] = v2; k3s[b] = k3; }

    int r = (bid % BLOCKS_PER_B) * 256 + threadIdx.x;
    unsigned key = score_key(maps[(size_t)b * NC * NCOARSE + r]);
    if ((int)(key >> 10) == ((v1 << 11) | v2)) {
        int w = 16 - __popc(bitsbuf[b*NCOARSE + r] & 0xFFFFu);
        if (w) atomicAdd(&hist3[b*1024 + (int)(key & 1023u)], w);
    }
}

// ---------- Phase C: parallel scan of hist3 + main fused reduction ----------
__global__ __launch_bounds__(256) void psel_phaseC(
    const float* __restrict__ maps, const float* __restrict__ gk,
    const unsigned* __restrict__ bitsbuf, const int* __restrict__ hist3,
    const int* __restrict__ v1s, const int* __restrict__ v2s,
    const int* __restrict__ k3s, const int* __restrict__ flb,
    float* __restrict__ acc)
{
    int bid = blockIdx.x;
    int b = bid / BLOCKS_PER_B;
    int fb = flb[b];
    unsigned thrkey = 0;
    if (!fb) {
        int ku;
        int v3 = bsel256<1024>(hist3 + b*1024, k3s[b], ku);
        thrkey = ((unsigned)v1s[b] << 21) | ((unsigned)v2s[b] << 10) | (unsigned)v3;
    }

    int r = (bid % BLOCKS_PER_B) * 256 + threadIdx.x;
    int cy = r / WC, cx = r % WC;

    float sig[NC]; float mv0 = 0.f, mv6 = 0.f;
    #pragma unroll
    for (int c = 0; c < NC; ++c) {
        float mv = maps[((size_t)(b*NC + c))*NCOARSE + r];
        if (c == 0) mv0 = mv;
        if (c == 6) mv6 = mv;
        sig[c] = 1.0f / (1.0f + expf(-mv));
    }
    bool at = mv0 > 0.0f;
    bool a5 = mv6 > 0.0f;
    bool cthr = fb || (score_key(mv0) >= thrkey);

    unsigned bits = bitsbuf[b*NCOARSE + r];
    unsigned mbits = bits >> 16, gbits = bits & 0xFFFFu;
    unsigned gmb = mbits & gbits;
    float cm  = (float)__popc(mbits);
    float cgm = (float)__popc(gmb);

    float cgkm[NK];
    float cg5mg = 0.f;
    #pragma unroll
    for (int k = 0; k < NK; ++k) {               // k-outer: 4 coherent row streams
        const float* gkb = gk + (size_t)(b*NK + k) * NFINE + (cy*4)*WF + cx*4;
        float s = 0.f, s5 = 0.f;
        #pragma unroll
        for (int row = 0; row < 4; ++row) {
            float4 k4 = *reinterpret_cast<const float4*>(gkb + row*WF);
            unsigned mrow = (mbits >> (4*row)) & 15u;
            unsigned grow = (gmb   >> (4*row)) & 15u;
            if (mrow & 1u) s += k4.x;
            if (mrow & 2u) s += k4.y;
            if (mrow & 4u) s += k4.z;
            if (mrow & 8u) s += k4.w;
            if (k == NK-1) {
                if (grow & 1u) s5 += k4.x;
                if (grow & 2u) s5 += k4.y;
                if (grow & 4u) s5 += k4.z;
                if (grow & 8u) s5 += k4.w;
            }
        }
        cgkm[k] = s;
        if (k == NK-1) cg5mg = s5;
    }

    float vals[NACC];
    float s0 = sig[0];
    vals[0] = s0 * cgm;                          // A_t
    vals[1] = s0 * s0 * (cthr ? cm : cgm);       // B_t (threshold term fused)
    vals[2] = cgm;                               // C_t
    vals[3] = cm;                                // S_cm
    vals[4] = at ? cgm : 0.f;                    // n11 text
    vals[5] = at ? cm  : 0.f;
    #pragma unroll
    for (int k = 0; k < NK; ++k) {
        float sk = sig[k+1];
        vals[6 + 3*k] = at ? sk * cgkm[k] : 0.f;       // A_k
        vals[7 + 3*k] = at ? sk * sk * cm : 0.f;       // B_k
        vals[8 + 3*k] = at ? cgkm[k] : 0.f;            // C_k
    }
    vals[24] = a5 ? cg5mg : 0.f;                 // m11 kernel-iou
    vals[25] = a5 ? cgm   : 0.f;
    vals[26] = cg5mg;

    #pragma unroll
    for (int i = 0; i < NACC; ++i) {
        #pragma unroll
        for (int off = 32; off; off >>= 1)
            vals[i] += __shfl_down(vals[i], off);
    }
    __shared__ float red[4][NACC];
    int wid = threadIdx.x >> 6, lane = threadIdx.x & 63;
    if (lane == 0) {
        #pragma unroll
        for (int i = 0; i < NACC; ++i) red[wid][i] = vals[i];
    }
    __syncthreads();
    if (threadIdx.x < NACC) {
        float s = red[0][threadIdx.x] + red[1][threadIdx.x]
                + red[2][threadIdx.x] + red[3][threadIdx.x];
        atomicAdd(&acc[b*ACC_STRIDE + threadIdx.x], s);
    }
}

// ---------- Phase D: final per-batch algebra + output sums ----------
__global__ __launch_bounds__(64) void psel_phaseD(
    const float* __restrict__ acc, float* __restrict__ out)
{
    int b = threadIdx.x;
    float l = 0.f, lt = 0.f, lk = 0.f, it = 0.f, ik = 0.f;
    if (b < NB) {
        const float* a = acc + b*ACC_STRIDE;
        float At = a[0], Bt = a[1], Ct = a[2], Sm = a[3], Satgm = a[4], Satm = a[5];
        lt = 1.f - 2.f*At / (Bt + Ct + 2.f*EPSF);
        float n11 = Satgm;
        float u1 = Satm + Ct - Satgm;
        float i0 = Sm - u1;
        float u0 = Sm - n11;
        it = 0.5f * (i0/(u0 + EPSF) + n11/(u1 + EPSF));
        float lks = 0.f;
        #pragma unroll
        for (int k = 0; k < NK; ++k) {
            float Ak = a[6+3*k], Bk = a[7+3*k], Ck = a[8+3*k];
            lks += 1.f - 2.f*Ak / (Bk + Ck + 2.f*EPSF);
        }
        lk = lks / (float)NK;
        float m11 = a[24], Sa5gm = a[25], Sg5 = a[26];
        float ku1 = Sa5gm + Sg5 - m11;
        float ki0 = Ct - ku1;
        float ku0 = Ct - m11;
        ik = 0.5f * (ki0/(ku0 + EPSF) + m11/(ku1 + EPSF));
        l = 0.7f*lt + 0.3f*lk;
    }
    #pragma unroll
    for (int off = 8; off; off >>= 1) {
        l  += __shfl_down(l,  off);
        lt += __shfl_down(lt, off);
        lk += __shfl_down(lk, off);
        it += __shfl_down(it, off);
        ik += __shfl_down(ik, off);
    }
    if (threadIdx.x == 0) {
        out[0] = l; out[1] = lt; out[2] = lk; out[3] = it; out[4] = ik;
    }
}

extern "C" void kernel_launch(void* const* d_in, const int* in_sizes, int n_in,
                              void* d_out, int out_size, void* d_ws, size_t ws_size,
                              hipStream_t stream) {
    const float* maps = (const float*)d_in[0];
    const float* gt   = (const float*)d_in[1];
    const float* gk   = (const float*)d_in[2];
    const float* tm   = (const float*)d_in[3];
    float* out = (float*)d_out;
    char* ws = (char*)d_ws;
    float*    acc     = (float*)ws;
    int*      pos_num = (int*)(ws + WS_POS);
    int*      neg_tot = (int*)(ws + WS_NEG);
    int*      v1s     = (int*)(ws + WS_V1);
    int*      k2s     = (int*)(ws + WS_K2);
    int*      v2s     = (int*)(ws + WS_V2);
    int*      k3s     = (int*)(ws + WS_K3);
    int*      flb     = (int*)(ws + WS_FLB);
    int*      hist1   = (int*)(ws + WS_H1);
    int*      hist2   = (int*)(ws + WS_H2);
    int*      hist3   = (int*)(ws + WS_H3);
    unsigned* bits    = (unsigned*)(ws + WS_BITS);

    psel_init   <<<WS_ZERO_BYTES/16/256, 256, 0, stream>>>((uint4*)ws);
    psel_phaseA <<<NB*BLOCKS_PER_B, 256, 0, stream>>>(maps, gt, tm, pos_num, neg_tot, hist1, bits);
    psel_phaseB2<<<NB*BLOCKS_PER_B, 256, 0, stream>>>(maps, bits, pos_num, neg_tot, hist1, hist2, v1s, k2s, flb);
    psel_phaseB4<<<NB*BLOCKS_PER_B, 256, 0, stream>>>(maps, bits, hist2, hist3, v1s, k2s, v2s, k3s, flb);
    psel_phaseC <<<NB*BLOCKS_PER_B, 256, 0, stream>>>(maps, gk, bits, hist3, v1s, v2s, k3s, flb, acc);
    psel_phaseD <<<1, 64, 0, stream>>>(acc, out);
}

// Round 7
// 67.329 us; speedup vs baseline: 1.1149x; 1.1149x over previous
//
#include <hip/hip_runtime.h>

#define NB 16
#define NC 7
#define NK 6
#define HC 160
#define WC 160
#define HF 640
#define WF 640
#define NCOARSE (HC*WC)             // 25600 coarse pixels per batch
#define NFINE   (HF*WF)             // 409600 fine pixels per batch
#define BLOCKS_PER_B (NCOARSE/256)  // 100
#define NQ4 (NCOARSE/4)             // 6400 float4/uint4 per batch
#define NACC 27
#define ACC_STRIDE 32
#define EPSF 1e-6f

// ---------------- ws layout (bytes) ----------------
// acc      float[16*32]   @ 0      (2048)  [zeroed by init]
// pos_num  int[16]        @ 2048           [zeroed by init]
// neg_tot  int[16]        @ 2112           [zeroed by init]
// thrkeys  uint[16]       @ 2176           [always written by B]
// bits     uint[409600]   @ 4096           [written by A]
#define WS_POS   2048
#define WS_NEG   2112
#define WS_THR   2176
#define WS_BITS  4096
#define WS_ZERO_BYTES 2176   // acc + pos + neg  (136 uint4)

__device__ __forceinline__ unsigned score_key(float s) {
    unsigned u = __float_as_uint(s);
    return (u & 0x80000000u) ? ~u : (u | 0x80000000u);
}

// ---------- init: zero acc + pos/neg counters ----------
__global__ __launch_bounds__(256) void psel_init(uint4* __restrict__ ws4) {
    int i = threadIdx.x;
    if (i < WS_ZERO_BYTES/16) ws4[i] = uint4{0u, 0u, 0u, 0u};
}

// ---------- Phase A: bit-pack g/m + per-batch pos/neg counts ----------
__global__ __launch_bounds__(256) void psel_phaseA(
    const float* __restrict__ gt, const float* __restrict__ tm,
    int* __restrict__ pos_num, int* __restrict__ neg_tot,
    unsigned* __restrict__ bitsbuf)
{
    int t = threadIdx.x;
    int bid = blockIdx.x;
    int b = bid / BLOCKS_PER_B;
    int r = (bid % BLOCKS_PER_B) * 256 + t;
    int cy = r / WC, cx = r % WC;
    const float* gtb = gt + (size_t)b * NFINE;
    const float* tmb = tm + (size_t)b * NFINE;
    unsigned gb = 0, mb = 0;
    #pragma unroll
    for (int row = 0; row < 4; ++row) {
        int off = (cy*4 + row)*WF + cx*4;
        float4 g4 = *reinterpret_cast<const float4*>(gtb + off);
        float4 m4 = *reinterpret_cast<const float4*>(tmb + off);
        unsigned sh = 4*row;
        gb |= ((g4.x > 0.5f) ? 1u : 0u) << (sh+0);
        gb |= ((g4.y > 0.5f) ? 1u : 0u) << (sh+1);
        gb |= ((g4.z > 0.5f) ? 1u : 0u) << (sh+2);
        gb |= ((g4.w > 0.5f) ? 1u : 0u) << (sh+3);
        mb |= ((m4.x > 0.5f) ? 1u : 0u) << (sh+0);
        mb |= ((m4.y > 0.5f) ? 1u : 0u) << (sh+1);
        mb |= ((m4.z > 0.5f) ? 1u : 0u) << (sh+2);
        mb |= ((m4.w > 0.5f) ? 1u : 0u) << (sh+3);
    }
    bitsbuf[b*NCOARSE + r] = (mb << 16) | gb;
    int posc = __popc(gb & mb);
    int negc = 16 - __popc(gb);

    #pragma unroll
    for (int off = 32; off; off >>= 1) {
        posc += __shfl_down(posc, off);
        negc += __shfl_down(negc, off);
    }
    __shared__ int sp[4], sn[4];
    int wid = t >> 6, lane = t & 63;
    if (lane == 0) { sp[wid] = posc; sn[wid] = negc; }
    __syncthreads();
    if (t == 0) {
        atomicAdd(&pos_num[b], sp[0]+sp[1]+sp[2]+sp[3]);
        atomicAdd(&neg_tot[b], sn[0]+sn[1]+sn[2]+sn[3]);
    }
}

// Block-wide (1024 thr) weighted descending select over LDS histogram.
// (general path only — never taken for the benchmark distribution)
template<int NBINS>
__device__ __forceinline__ int bsel(int* __restrict__ lh, int* __restrict__ ws16,
                                    int* __restrict__ wsuf, int* __restrict__ res,
                                    int k, int& krem)
{
    constexpr int CH = NBINS / 1024;
    int t = threadIdx.x, wid = t >> 6, lane = t & 63;
    __syncthreads();                 // histogram atomics complete
    int c = 0;
    #pragma unroll
    for (int j = 0; j < CH; ++j) c += lh[t*CH + j];
    int s = c;
    #pragma unroll
    for (int off = 1; off < 64; off <<= 1) {
        int v = __shfl_down(s, off);
        if (lane + off < 64) s += v;
    }
    if (lane == 0) ws16[wid] = s;
    __syncthreads();
    if (t < 16) {
        int sum = 0;
        for (int j = t; j < 16; ++j) sum += ws16[j];
        wsuf[t] = sum;
    }
    if (t == 0) { wsuf[16] = 0; res[0] = 0; res[1] = k; }
    __syncthreads();
    int G = s + wsuf[wid + 1];
    int above = G - c;
    if (G >= k && above < k) {
        int cum = above;
        for (int u = t*CH + CH - 1; u >= t*CH; --u) {
            cum += lh[u];
            if (cum >= k) { res[0] = u; res[1] = k - (cum - lh[u]); break; }
        }
    }
    __syncthreads();
    int bin = res[0]; krem = res[1];
    __syncthreads();
    return bin;
}

// ---------- Phase B: OHEM threshold. Trivial when neg_num==neg_total (always
// true for this distribution): threshold = min neg score => every pixel
// selected => thrkey=0. Full weighted radix kept for the general case. ----------
__global__ __launch_bounds__(1024) void psel_phaseB(
    const float* __restrict__ maps, const unsigned* __restrict__ bitsbuf,
    const int* __restrict__ pos_num, const int* __restrict__ neg_tot,
    unsigned* __restrict__ thrkeys)
{
    int b = blockIdx.x;
    int t = threadIdx.x;
    int pos = pos_num[b];
    long long negT = neg_tot[b];
    long long nn = (long long)pos * 3; if (nn > negT) nn = negT;
    int k = (int)nn;
    if (pos == 0 || k == 0 || k == (int)negT) {
        // fallback (sel=m) or select-all — both mean cthr true everywhere
        if (t == 0) thrkeys[b] = 0u;
        return;
    }

    __shared__ unsigned wpack[NQ4];  // 4 packed 8-bit weights per uint
    __shared__ int lh[2048];
    __shared__ int ws16[16], wsuf[17], res[2];
    const float4* mp4 = reinterpret_cast<const float4*>(maps + (size_t)b * NC * NCOARSE);
    const uint4*  bb4 = reinterpret_cast<const uint4*>(bitsbuf + (size_t)b * NCOARSE);

    // ---- pass 1: weight cache + top-11-bit histogram ----
    for (int j = t; j < 2048; j += 1024) lh[j] = 0;
    __syncthreads();
    for (int i4 = t; i4 < NQ4; i4 += 1024) {
        float4 m4 = mp4[i4];
        uint4  b4 = bb4[i4];
        float    mv[4] = {m4.x, m4.y, m4.z, m4.w};
        unsigned bv[4] = {b4.x, b4.y, b4.z, b4.w};
        unsigned pk = 0;
        #pragma unroll
        for (int j = 0; j < 4; ++j) {
            int w = 16 - __popc(bv[j] & 0xFFFFu);
            pk |= (unsigned)w << (8*j);
            if (w) atomicAdd(&lh[score_key(mv[j]) >> 21], w);
        }
        wpack[i4] = pk;
    }
    int v = bsel<2048>(lh, ws16, wsuf, res, k, k);
    unsigned prefix = (unsigned)v;

    // ---- pass 2: middle 11 bits ----
    for (int j = t; j < 2048; j += 1024) lh[j] = 0;
    __syncthreads();
    for (int i4 = t; i4 < NQ4; i4 += 1024) {
        float4 m4 = mp4[i4];
        unsigned pk = wpack[i4];
        float mv[4] = {m4.x, m4.y, m4.z, m4.w};
        #pragma unroll
        for (int j = 0; j < 4; ++j) {
            int w = (pk >> (8*j)) & 255;
            if (w) {
                unsigned key = score_key(mv[j]);
                if ((key >> 21) == prefix) atomicAdd(&lh[(key >> 10) & 2047u], w);
            }
        }
    }
    v = bsel<2048>(lh, ws16, wsuf, res, k, k);
    prefix = (prefix << 11) | (unsigned)v;

    // ---- pass 3: low 10 bits ----
    for (int j = t; j < 1024; j += 1024) lh[j] = 0;
    __syncthreads();
    for (int i4 = t; i4 < NQ4; i4 += 1024) {
        float4 m4 = mp4[i4];
        unsigned pk = wpack[i4];
        float mv[4] = {m4.x, m4.y, m4.z, m4.w};
        #pragma unroll
        for (int j = 0; j < 4; ++j) {
            int w = (pk >> (8*j)) & 255;
            if (w) {
                unsigned key = score_key(mv[j]);
                if ((key >> 10) == prefix) atomicAdd(&lh[key & 1023u], w);
            }
        }
    }
    v = bsel<1024>(lh, ws16, wsuf, res, k, k);
    if (t == 0) thrkeys[b] = (prefix << 10) | (unsigned)v;
}

// ---------- Phase C: main fused reduction ----------
__global__ __launch_bounds__(256) void psel_phaseC(
    const float* __restrict__ maps, const float* __restrict__ gk,
    const unsigned* __restrict__ bitsbuf, const unsigned* __restrict__ thrkeys,
    float* __restrict__ acc)
{
    int bid = blockIdx.x;
    int b = bid / BLOCKS_PER_B;
    unsigned thrkey = thrkeys[b];

    int r = (bid % BLOCKS_PER_B) * 256 + threadIdx.x;
    int cy = r / WC, cx = r % WC;

    float sig[NC]; float mv0 = 0.f, mv6 = 0.f;
    #pragma unroll
    for (int c = 0; c < NC; ++c) {
        float mv = maps[((size_t)(b*NC + c))*NCOARSE + r];
        if (c == 0) mv0 = mv;
        if (c == 6) mv6 = mv;
        sig[c] = 1.0f / (1.0f + expf(-mv));
    }
    bool at = mv0 > 0.0f;
    bool a5 = mv6 > 0.0f;
    bool cthr = score_key(mv0) >= thrkey;   // thrkey==0 => always true

    unsigned bits = bitsbuf[b*NCOARSE + r];
    unsigned mbits = bits >> 16, gbits = bits & 0xFFFFu;
    unsigned gmb = mbits & gbits;
    float cm  = (float)__popc(mbits);
    float cgm = (float)__popc(gmb);

    float cgkm[NK];
    float cg5mg = 0.f;
    #pragma unroll
    for (int k = 0; k < NK; ++k) {               // k-outer: 4 coherent row streams
        const float* gkb = gk + (size_t)(b*NK + k) * NFINE + (cy*4)*WF + cx*4;
        float s = 0.f, s5 = 0.f;
        #pragma unroll
        for (int row = 0; row < 4; ++row) {
            float4 k4 = *reinterpret_cast<const float4*>(gkb + row*WF);
            unsigned mrow = (mbits >> (4*row)) & 15u;
            unsigned grow = (gmb   >> (4*row)) & 15u;
            if (mrow & 1u) s += k4.x;
            if (mrow & 2u) s += k4.y;
            if (mrow & 4u) s += k4.z;
            if (mrow & 8u) s += k4.w;
            if (k == NK-1) {
                if (grow & 1u) s5 += k4.x;
                if (grow & 2u) s5 += k4.y;
                if (grow & 4u) s5 += k4.z;
                if (grow & 8u) s5 += k4.w;
            }
        }
        cgkm[k] = s;
        if (k == NK-1) cg5mg = s5;
    }

    float vals[NACC];
    float s0 = sig[0];
    vals[0] = s0 * cgm;                          // A_t
    vals[1] = s0 * s0 * (cthr ? cm : cgm);       // B_t
    vals[2] = cgm;                               // C_t
    vals[3] = cm;                                // S_cm
    vals[4] = at ? cgm : 0.f;                    // n11 text
    vals[5] = at ? cm  : 0.f;
    #pragma unroll
    for (int k = 0; k < NK; ++k) {
        float sk = sig[k+1];
        vals[6 + 3*k] = at ? sk * cgkm[k] : 0.f;       // A_k
        vals[7 + 3*k] = at ? sk * sk * cm : 0.f;       // B_k
        vals[8 + 3*k] = at ? cgkm[k] : 0.f;            // C_k
    }
    vals[24] = a5 ? cg5mg : 0.f;                 // m11 kernel-iou
    vals[25] = a5 ? cgm   : 0.f;
    vals[26] = cg5mg;

    #pragma unroll
    for (int i = 0; i < NACC; ++i) {
        #pragma unroll
        for (int off = 32; off; off >>= 1)
            vals[i] += __shfl_down(vals[i], off);
    }
    __shared__ float red[4][NACC];
    int wid = threadIdx.x >> 6, lane = threadIdx.x & 63;
    if (lane == 0) {
        #pragma unroll
        for (int i = 0; i < NACC; ++i) red[wid][i] = vals[i];
    }
    __syncthreads();
    if (threadIdx.x < NACC) {
        float s = red[0][threadIdx.x] + red[1][threadIdx.x]
                + red[2][threadIdx.x] + red[3][threadIdx.x];
        atomicAdd(&acc[b*ACC_STRIDE + threadIdx.x], s);
    }
}

// ---------- Phase D: final per-batch algebra + output sums ----------
__global__ __launch_bounds__(64) void psel_phaseD(
    const float* __restrict__ acc, float* __restrict__ out)
{
    int b = threadIdx.x;
    float l = 0.f, lt = 0.f, lk = 0.f, it = 0.f, ik = 0.f;
    if (b < NB) {
        const float* a = acc + b*ACC_STRIDE;
        float At = a[0], Bt = a[1], Ct = a[2], Sm = a[3], Satgm = a[4], Satm = a[5];
        lt = 1.f - 2.f*At / (Bt + Ct + 2.f*EPSF);
        float n11 = Satgm;
        float u1 = Satm + Ct - Satgm;
        float i0 = Sm - u1;
        float u0 = Sm - n11;
        it = 0.5f * (i0/(u0 + EPSF) + n11/(u1 + EPSF));
        float lks = 0.f;
        #pragma unroll
        for (int k = 0; k < NK; ++k) {
            float Ak = a[6+3*k], Bk = a[7+3*k], Ck = a[8+3*k];
            lks += 1.f - 2.f*Ak / (Bk + Ck + 2.f*EPSF);
        }
        lk = lks / (float)NK;
        float m11 = a[24], Sa5gm = a[25], Sg5 = a[26];
        float ku1 = Sa5gm + Sg5 - m11;
        float ki0 = Ct - ku1;
        float ku0 = Ct - m11;
        ik = 0.5f * (ki0/(ku0 + EPSF) + m11/(ku1 + EPSF));
        l = 0.7f*lt + 0.3f*lk;
    }
    #pragma unroll
    for (int off = 8; off; off >>= 1) {
        l  += __shfl_down(l,  off);
        lt += __shfl_down(lt, off);
        lk += __shfl_down(lk, off);
        it += __shfl_down(it, off);
        ik += __shfl_down(ik, off);
    }
    if (threadIdx.x == 0) {
        out[0] = l; out[1] = lt; out[2] = lk; out[3] = it; out[4] = ik;
    }
}

extern "C" void kernel_launch(void* const* d_in, const int* in_sizes, int n_in,
                              void* d_out, int out_size, void* d_ws, size_t ws_size,
                              hipStream_t stream) {
    const float* maps = (const float*)d_in[0];
    const float* gt   = (const float*)d_in[1];
    const float* gk   = (const float*)d_in[2];
    const float* tm   = (const float*)d_in[3];
    float* out = (float*)d_out;
    char* ws = (char*)d_ws;
    float*    acc     = (float*)ws;
    int*      pos_num = (int*)(ws + WS_POS);
    int*      neg_tot = (int*)(ws + WS_NEG);
    unsigned* thrkeys = (unsigned*)(ws + WS_THR);
    unsigned* bits    = (unsigned*)(ws + WS_BITS);

    psel_init  <<<1, 256, 0, stream>>>((uint4*)ws);
    psel_phaseA<<<NB*BLOCKS_PER_B, 256, 0, stream>>>(gt, tm, pos_num, neg_tot, bits);
    psel_phaseB<<<NB, 1024, 0, stream>>>(maps, bits, pos_num, neg_tot, thrkeys);
    psel_phaseC<<<NB*BLOCKS_PER_B, 256, 0, stream>>>(maps, gk, bits, thrkeys, acc);
    psel_phaseD<<<1, 64, 0, stream>>>(acc, out);
}

// Round 8
// 59.386 us; speedup vs baseline: 1.2640x; 1.1338x over previous
//
#include <hip/hip_runtime.h>

#define NB 16
#define NC 7
#define NK 6
#define HC 160
#define WC 160
#define HF 640
#define WF 640
#define NCOARSE (HC*WC)             // 25600 coarse pixels per batch
#define NFINE   (HF*WF)             // 409600 fine pixels per batch
#define BLOCKS_PER_B (NCOARSE/256)  // 100
#define NQ4 (NCOARSE/4)             // 6400 float4/uint4 per batch
#define NACC 27
#define EPSF 1e-6f

// ---------------- ws layout (bytes) ----------------
// pf       float[1600*32]  @ 0        (204800)  [fully written by K1]
// pi       int[1600*2]     @ 204800   (12800)   [fully written by K1]
// metrics  float[16*8]     @ 217600   (512)     [fully written by B]
// bits     uint[409600]    @ 218112   (1638400) [fully written by K1]
#define WS_PI    204800
#define WS_MET   217600
#define WS_BITS  218112

__device__ __forceinline__ unsigned score_key(float s) {
    unsigned u = __float_as_uint(s);
    return (u & 0x80000000u) ? ~u : (u | 0x80000000u);
}

// ---------- K1: fused bit-pack + main reduction (threshold-independent) ----------
__global__ __launch_bounds__(256) void psel_K1(
    const float* __restrict__ maps, const float* __restrict__ gt,
    const float* __restrict__ gk, const float* __restrict__ tm,
    unsigned* __restrict__ bitsbuf, float* __restrict__ pf, int* __restrict__ pi)
{
    int t = threadIdx.x;
    int bid = blockIdx.x;
    int b = bid / BLOCKS_PER_B;
    int r = (bid % BLOCKS_PER_B) * 256 + t;
    int cy = r / WC, cx = r % WC;

    // ---- g/m bits (in registers) ----
    const float* gtb = gt + (size_t)b * NFINE;
    const float* tmb = tm + (size_t)b * NFINE;
    unsigned gb = 0, mb = 0;
    #pragma unroll
    for (int row = 0; row < 4; ++row) {
        int off = (cy*4 + row)*WF + cx*4;
        float4 g4 = *reinterpret_cast<const float4*>(gtb + off);
        float4 m4 = *reinterpret_cast<const float4*>(tmb + off);
        unsigned sh = 4*row;
        gb |= ((g4.x > 0.5f) ? 1u : 0u) << (sh+0);
        gb |= ((g4.y > 0.5f) ? 1u : 0u) << (sh+1);
        gb |= ((g4.z > 0.5f) ? 1u : 0u) << (sh+2);
        gb |= ((g4.w > 0.5f) ? 1u : 0u) << (sh+3);
        mb |= ((m4.x > 0.5f) ? 1u : 0u) << (sh+0);
        mb |= ((m4.y > 0.5f) ? 1u : 0u) << (sh+1);
        mb |= ((m4.z > 0.5f) ? 1u : 0u) << (sh+2);
        mb |= ((m4.w > 0.5f) ? 1u : 0u) << (sh+3);
    }
    bitsbuf[b*NCOARSE + r] = (mb << 16) | gb;   // for phase B only
    unsigned gmb = gb & mb;
    int posc = __popc(gmb);
    int negc = 16 - __popc(gb);
    float cm  = (float)__popc(mb);
    float cgm = (float)posc;

    // ---- maps + sigmoids ----
    float sig[NC]; float mv0 = 0.f, mv6 = 0.f;
    #pragma unroll
    for (int c = 0; c < NC; ++c) {
        float mv = maps[((size_t)(b*NC + c))*NCOARSE + r];
        if (c == 0) mv0 = mv;
        if (c == 6) mv6 = mv;
        sig[c] = 1.0f / (1.0f + expf(-mv));
    }
    bool at = mv0 > 0.0f;
    bool a5 = mv6 > 0.0f;

    // ---- gk masked sums (k-outer, coherent row streams) ----
    float cgkm[NK];
    float cg5mg = 0.f;
    #pragma unroll
    for (int k = 0; k < NK; ++k) {
        const float* gkb = gk + (size_t)(b*NK + k) * NFINE + (cy*4)*WF + cx*4;
        float s = 0.f, s5 = 0.f;
        #pragma unroll
        for (int row = 0; row < 4; ++row) {
            float4 k4 = *reinterpret_cast<const float4*>(gkb + row*WF);
            unsigned mrow = (mb  >> (4*row)) & 15u;
            unsigned grow = (gmb >> (4*row)) & 15u;
            if (mrow & 1u) s += k4.x;
            if (mrow & 2u) s += k4.y;
            if (mrow & 4u) s += k4.z;
            if (mrow & 8u) s += k4.w;
            if (k == NK-1) {
                if (grow & 1u) s5 += k4.x;
                if (grow & 2u) s5 += k4.y;
                if (grow & 4u) s5 += k4.z;
                if (grow & 8u) s5 += k4.w;
            }
        }
        cgkm[k] = s;
        if (k == NK-1) cg5mg = s5;
    }

    float vals[NACC];
    float s0 = sig[0];
    vals[0] = s0 * cgm;                          // A_t
    vals[1] = s0 * s0 * cgm;                     // B_t threshold-indep part (B adds rest)
    vals[2] = cgm;                               // C_t
    vals[3] = cm;                                // S_cm
    vals[4] = at ? cgm : 0.f;                    // n11 text
    vals[5] = at ? cm  : 0.f;
    #pragma unroll
    for (int k = 0; k < NK; ++k) {
        float sk = sig[k+1];
        vals[6 + 3*k] = at ? sk * cgkm[k] : 0.f;       // A_k
        vals[7 + 3*k] = at ? sk * sk * cm : 0.f;       // B_k
        vals[8 + 3*k] = at ? cgkm[k] : 0.f;            // C_k
    }
    vals[24] = a5 ? cg5mg : 0.f;                 // m11 kernel-iou
    vals[25] = a5 ? cgm   : 0.f;
    vals[26] = cg5mg;

    // ---- block reduce 27 floats + 2 ints, plain store (no atomics) ----
    #pragma unroll
    for (int i = 0; i < NACC; ++i) {
        #pragma unroll
        for (int off = 32; off; off >>= 1)
            vals[i] += __shfl_down(vals[i], off);
    }
    #pragma unroll
    for (int off = 32; off; off >>= 1) {
        posc += __shfl_down(posc, off);
        negc += __shfl_down(negc, off);
    }
    __shared__ float red[4][NACC];
    __shared__ int sp[4], sn[4];
    int wid = t >> 6, lane = t & 63;
    if (lane == 0) {
        #pragma unroll
        for (int i = 0; i < NACC; ++i) red[wid][i] = vals[i];
        sp[wid] = posc; sn[wid] = negc;
    }
    __syncthreads();
    if (t < NACC)
        pf[bid*32 + t] = red[0][t] + red[1][t] + red[2][t] + red[3][t];
    if (t == 0) {
        pi[2*bid]   = sp[0]+sp[1]+sp[2]+sp[3];
        pi[2*bid+1] = sn[0]+sn[1]+sn[2]+sn[3];
    }
}

// Block-wide (1024 thr) weighted descending select over LDS histogram.
// (general path only — never taken for the benchmark distribution)
template<int NBINS>
__device__ __forceinline__ int bsel(int* __restrict__ lh, int* __restrict__ ws16,
                                    int* __restrict__ wsuf, int* __restrict__ res,
                                    int k, int& krem)
{
    constexpr int CH = NBINS / 1024;
    int t = threadIdx.x, wid = t >> 6, lane = t & 63;
    __syncthreads();                 // histogram atomics complete
    int c = 0;
    #pragma unroll
    for (int j = 0; j < CH; ++j) c += lh[t*CH + j];
    int s = c;
    #pragma unroll
    for (int off = 1; off < 64; off <<= 1) {
        int v = __shfl_down(s, off);
        if (lane + off < 64) s += v;
    }
    if (lane == 0) ws16[wid] = s;
    __syncthreads();
    if (t < 16) {
        int sum = 0;
        for (int j = t; j < 16; ++j) sum += ws16[j];
        wsuf[t] = sum;
    }
    if (t == 0) { wsuf[16] = 0; res[0] = 0; res[1] = k; }
    __syncthreads();
    int G = s + wsuf[wid + 1];
    int above = G - c;
    if (G >= k && above < k) {
        int cum = above;
        for (int u = t*CH + CH - 1; u >= t*CH; --u) {
            cum += lh[u];
            if (cum >= k) { res[0] = u; res[1] = k - (cum - lh[u]); break; }
        }
    }
    __syncthreads();
    int bin = res[0]; krem = res[1];
    __syncthreads();
    return bin;
}

// ---------- B: threshold + threshold-term + per-batch finalize ----------
__global__ __launch_bounds__(1024) void psel_B(
    const float* __restrict__ maps, const unsigned* __restrict__ bitsbuf,
    const float* __restrict__ pf, const int* __restrict__ pi,
    float* __restrict__ metrics)
{
    __shared__ unsigned wpack[NQ4];
    __shared__ int lh[2048];
    __shared__ int ws16[16], wsuf[17], res[2];
    __shared__ int ipn[16][2];
    __shared__ float fred[16][NACC];
    __shared__ float s16[16];
    __shared__ float fin[NACC];
    __shared__ float thrT_sh;
    int b = blockIdx.x, t = threadIdx.x;
    int wid = t >> 6, lane = t & 63;

    // ---- pos/neg from pi ----
    int p = 0, n = 0;
    if (t < BLOCKS_PER_B) { p = pi[(b*BLOCKS_PER_B + t)*2]; n = pi[(b*BLOCKS_PER_B + t)*2 + 1]; }
    #pragma unroll
    for (int off = 32; off; off >>= 1) {
        p += __shfl_down(p, off);
        n += __shfl_down(n, off);
    }
    if (lane == 0) { ipn[wid][0] = p; ipn[wid][1] = n; }
    __syncthreads();
    if (t == 0) {
        int P = 0, N = 0;
        for (int j = 0; j < 16; ++j) { P += ipn[j][0]; N += ipn[j][1]; }
        res[0] = P; res[1] = N;
    }
    __syncthreads();
    int pos = res[0], negT = res[1];
    long long nn = (long long)pos * 3; if (nn > negT) nn = negT;
    int k = (int)nn;
    unsigned thrkey = 0;

    const float4* mp4 = reinterpret_cast<const float4*>(maps + (size_t)b * NC * NCOARSE);
    const uint4*  bb4 = reinterpret_cast<const uint4*>(bitsbuf + (size_t)b * NCOARSE);

    if (!(pos == 0 || k == 0 || k == negT)) {
        // ---- general weighted radix select (not taken for this distribution) ----
        for (int j = t; j < 2048; j += 1024) lh[j] = 0;
        __syncthreads();
        for (int i4 = t; i4 < NQ4; i4 += 1024) {
            float4 m4 = mp4[i4];
            uint4  b4 = bb4[i4];
            float    mv[4] = {m4.x, m4.y, m4.z, m4.w};
            unsigned bv[4] = {b4.x, b4.y, b4.z, b4.w};
            unsigned pk = 0;
            #pragma unroll
            for (int j = 0; j < 4; ++j) {
                int w = 16 - __popc(bv[j] & 0xFFFFu);
                pk |= (unsigned)w << (8*j);
                if (w) atomicAdd(&lh[score_key(mv[j]) >> 21], w);
            }
            wpack[i4] = pk;
        }
        int v = bsel<2048>(lh, ws16, wsuf, res, k, k);
        unsigned prefix = (unsigned)v;

        for (int j = t; j < 2048; j += 1024) lh[j] = 0;
        __syncthreads();
        for (int i4 = t; i4 < NQ4; i4 += 1024) {
            float4 m4 = mp4[i4];
            unsigned pk = wpack[i4];
            float mv[4] = {m4.x, m4.y, m4.z, m4.w};
            #pragma unroll
            for (int j = 0; j < 4; ++j) {
                int w = (pk >> (8*j)) & 255;
                if (w) {
                    unsigned key = score_key(mv[j]);
                    if ((key >> 21) == prefix) atomicAdd(&lh[(key >> 10) & 2047u], w);
                }
            }
        }
        v = bsel<2048>(lh, ws16, wsuf, res, k, k);
        prefix = (prefix << 11) | (unsigned)v;

        for (int j = t; j < 1024; j += 1024) lh[j] = 0;
        __syncthreads();
        for (int i4 = t; i4 < NQ4; i4 += 1024) {
            float4 m4 = mp4[i4];
            unsigned pk = wpack[i4];
            float mv[4] = {m4.x, m4.y, m4.z, m4.w};
            #pragma unroll
            for (int j = 0; j < 4; ++j) {
                int w = (pk >> (8*j)) & 255;
                if (w) {
                    unsigned key = score_key(mv[j]);
                    if ((key >> 10) == prefix) atomicAdd(&lh[key & 1023u], w);
                }
            }
        }
        v = bsel<1024>(lh, ws16, wsuf, res, k, k);
        thrkey = (prefix << 10) | (unsigned)v;
    }

    // ---- threshold term: sum over selected coarse pixels of s0^2*(cm-cgm) ----
    float ssum = 0.f;
    for (int i4 = t; i4 < NQ4; i4 += 1024) {
        float4 m4 = mp4[i4];
        uint4  b4 = bb4[i4];
        float    mv[4] = {m4.x, m4.y, m4.z, m4.w};
        unsigned bv[4] = {b4.x, b4.y, b4.z, b4.w};
        #pragma unroll
        for (int j = 0; j < 4; ++j) {
            unsigned w = bv[j];
            float d = (float)(__popc(w >> 16) - __popc(w & (w >> 16) & 0xFFFFu));
            if (d > 0.f && score_key(mv[j]) >= thrkey) {
                float s = 1.0f / (1.0f + expf(-mv[j]));
                ssum += s * s * d;
            }
        }
    }
    #pragma unroll
    for (int off = 32; off; off >>= 1) ssum += __shfl_down(ssum, off);
    if (lane == 0) s16[wid] = ssum;

    // ---- reduce pf over this batch's 100 blocks ----
    float loc[NACC];
    #pragma unroll
    for (int j = 0; j < NACC; ++j) loc[j] = 0.f;
    if (t < BLOCKS_PER_B) {
        const float* row = pf + (size_t)(b*BLOCKS_PER_B + t) * 32;
        #pragma unroll
        for (int j = 0; j < NACC; ++j) loc[j] = row[j];
    }
    #pragma unroll
    for (int j = 0; j < NACC; ++j) {
        #pragma unroll
        for (int off = 32; off; off >>= 1)
            loc[j] += __shfl_down(loc[j], off);
    }
    if (lane == 0) {
        #pragma unroll
        for (int j = 0; j < NACC; ++j) fred[wid][j] = loc[j];
    }
    __syncthreads();
    if (t < NACC) {
        float s = 0.f;
        for (int w = 0; w < 16; ++w) s += fred[w][t];
        fin[t] = s;
    }
    if (t == 32) {
        float tt = 0.f;
        for (int j = 0; j < 16; ++j) tt += s16[j];
        thrT_sh = tt;
    }
    __syncthreads();

    // ---- per-batch algebra ----
    if (t == 0) {
        const float* a = fin;
        float At = a[0], Bt = a[1] + thrT_sh, Ct = a[2], Sm = a[3], Satgm = a[4], Satm = a[5];
        float lt = 1.f - 2.f*At / (Bt + Ct + 2.f*EPSF);
        float n11 = Satgm;
        float u1 = Satm + Ct - Satgm;
        float i0 = Sm - u1;
        float u0 = Sm - n11;
        float it = 0.5f * (i0/(u0 + EPSF) + n11/(u1 + EPSF));
        float lks = 0.f;
        #pragma unroll
        for (int kk = 0; kk < NK; ++kk) {
            float Ak = a[6+3*kk], Bk = a[7+3*kk], Ck = a[8+3*kk];
            lks += 1.f - 2.f*Ak / (Bk + Ck + 2.f*EPSF);
        }
        float lk = lks / (float)NK;
        float m11 = a[24], Sa5gm = a[25], Sg5 = a[26];
        float ku1 = Sa5gm + Sg5 - m11;
        float ki0 = Ct - ku1;
        float ku0 = Ct - m11;
        float ik = 0.5f * (ki0/(ku0 + EPSF) + m11/(ku1 + EPSF));
        float l = 0.7f*lt + 0.3f*lk;
        metrics[b*8 + 0] = l;
        metrics[b*8 + 1] = lt;
        metrics[b*8 + 2] = lk;
        metrics[b*8 + 3] = it;
        metrics[b*8 + 4] = ik;
    }
}

// ---------- D: sum 16x5 metrics ----------
__global__ __launch_bounds__(64) void psel_D(
    const float* __restrict__ metrics, float* __restrict__ out)
{
    int t = threadIdx.x;
    float v[5] = {0.f, 0.f, 0.f, 0.f, 0.f};
    if (t < NB) {
        #pragma unroll
        for (int j = 0; j < 5; ++j) v[j] = metrics[t*8 + j];
    }
    #pragma unroll
    for (int off = 8; off; off >>= 1) {
        #pragma unroll
        for (int j = 0; j < 5; ++j) v[j] += __shfl_down(v[j], off);
    }
    if (t == 0) {
        #pragma unroll
        for (int j = 0; j < 5; ++j) out[j] = v[j];
    }
}

extern "C" void kernel_launch(void* const* d_in, const int* in_sizes, int n_in,
                              void* d_out, int out_size, void* d_ws, size_t ws_size,
                              hipStream_t stream) {
    const float* maps = (const float*)d_in[0];
    const float* gt   = (const float*)d_in[1];
    const float* gk   = (const float*)d_in[2];
    const float* tm   = (const float*)d_in[3];
    float* out = (float*)d_out;
    char* ws = (char*)d_ws;
    float*    pf      = (float*)ws;
    int*      pi      = (int*)(ws + WS_PI);
    float*    metrics = (float*)(ws + WS_MET);
    unsigned* bits    = (unsigned*)(ws + WS_BITS);

    psel_K1<<<NB*BLOCKS_PER_B, 256, 0, stream>>>(maps, gt, gk, tm, bits, pf, pi);
    psel_B <<<NB, 1024, 0, stream>>>(maps, bits, pf, pi, metrics);
    psel_D <<<1, 64, 0, stream>>>(metrics, out);
}

// Round 9
// 45.970 us; speedup vs baseline: 1.6329x; 1.2918x over previous
//
#include <hip/hip_runtime.h>

#define NB 16
#define NC 7
#define NK 6
#define HC 160
#define WC 160
#define HF 640
#define WF 640
#define NCOARSE (HC*WC)             // 25600 coarse pixels per batch
#define NFINE   (HF*WF)             // 409600 fine pixels per batch
#define NQ4 (NCOARSE/4)             // 6400 float4/uint4 per batch
#define ITER 2
#define CHUNKS_PER_B 50             // 100 chunks of 256 / ITER
#define KBLOCKS (NB*CHUNKS_PER_B)   // 800
#define NACC 28                     // 27 + threshold-indep d-term
#define EPSF 1e-6f

// ---------------- ws layout (bytes) ----------------
// pf       float[800*32]   @ 0        (102400)  [fully written by K1]
// pi       int[800*2]      @ 102400   (6400)    [fully written by K1]
// metrics  float[16*8]     @ 108800   (512)     [fully written by B]
// bits     uint[409600]    @ 109312   (1638400) [fully written by K1]
#define WS_PI    102400
#define WS_MET   108800
#define WS_BITS  109312

__device__ __forceinline__ unsigned score_key(float s) {
    unsigned u = __float_as_uint(s);
    return (u & 0x80000000u) ? ~u : (u | 0x80000000u);
}

// ---------- K1: fused bit-pack + main reduction (threshold-independent) ----------
__global__ __launch_bounds__(256) void psel_K1(
    const float* __restrict__ maps, const float* __restrict__ gt,
    const float* __restrict__ gk, const float* __restrict__ tm,
    unsigned* __restrict__ bitsbuf, float* __restrict__ pf, int* __restrict__ pi)
{
    int t = threadIdx.x;
    int bid = blockIdx.x;
    int b = bid / CHUNKS_PER_B;
    int c0 = (bid % CHUNKS_PER_B) * ITER;

    float acc[NACC];
    #pragma unroll
    for (int i = 0; i < NACC; ++i) acc[i] = 0.f;
    int posA = 0, negA = 0;

    const float* gtb = gt + (size_t)b * NFINE;
    const float* tmb = tm + (size_t)b * NFINE;

    #pragma unroll
    for (int it = 0; it < ITER; ++it) {
        int r = (c0 + it) * 256 + t;
        int cy = r / WC, cx = r % WC;

        // ---- issue ALL loads for this pixel up front (ILP) ----
        float4 g4[4], m4[4];
        #pragma unroll
        for (int row = 0; row < 4; ++row) {
            int off = (cy*4 + row)*WF + cx*4;
            g4[row] = *reinterpret_cast<const float4*>(gtb + off);
            m4[row] = *reinterpret_cast<const float4*>(tmb + off);
        }
        float mv[NC];
        #pragma unroll
        for (int c = 0; c < NC; ++c)
            mv[c] = maps[((size_t)(b*NC + c))*NCOARSE + r];
        float4 k4[NK][4];
        #pragma unroll
        for (int k = 0; k < NK; ++k) {
            const float* gkb = gk + (size_t)(b*NK + k) * NFINE + (cy*4)*WF + cx*4;
            #pragma unroll
            for (int row = 0; row < 4; ++row)
                k4[k][row] = *reinterpret_cast<const float4*>(gkb + row*WF);
        }

        // ---- bits ----
        unsigned gb = 0, mb = 0;
        #pragma unroll
        for (int row = 0; row < 4; ++row) {
            unsigned sh = 4*row;
            gb |= ((g4[row].x > 0.5f) ? 1u : 0u) << (sh+0);
            gb |= ((g4[row].y > 0.5f) ? 1u : 0u) << (sh+1);
            gb |= ((g4[row].z > 0.5f) ? 1u : 0u) << (sh+2);
            gb |= ((g4[row].w > 0.5f) ? 1u : 0u) << (sh+3);
            mb |= ((m4[row].x > 0.5f) ? 1u : 0u) << (sh+0);
            mb |= ((m4[row].y > 0.5f) ? 1u : 0u) << (sh+1);
            mb |= ((m4[row].z > 0.5f) ? 1u : 0u) << (sh+2);
            mb |= ((m4[row].w > 0.5f) ? 1u : 0u) << (sh+3);
        }
        bitsbuf[b*NCOARSE + r] = (mb << 16) | gb;
        unsigned gmb = gb & mb;
        posA += __popc(gmb);
        negA += 16 - __popc(gb);
        float cm  = (float)__popc(mb);
        float cgm = (float)__popc(gmb);

        // ---- sigmoids ----
        float sig[NC];
        #pragma unroll
        for (int c = 0; c < NC; ++c) sig[c] = 1.0f / (1.0f + expf(-mv[c]));
        bool at = mv[0] > 0.0f;
        bool a5 = mv[6] > 0.0f;

        // ---- gk masked sums ----
        float cgkm[NK];
        float cg5mg = 0.f;
        #pragma unroll
        for (int k = 0; k < NK; ++k) {
            float s = 0.f;
            #pragma unroll
            for (int row = 0; row < 4; ++row) {
                unsigned mrow = (mb >> (4*row)) & 15u;
                if (mrow & 1u) s += k4[k][row].x;
                if (mrow & 2u) s += k4[k][row].y;
                if (mrow & 4u) s += k4[k][row].z;
                if (mrow & 8u) s += k4[k][row].w;
            }
            cgkm[k] = s;
        }
        #pragma unroll
        for (int row = 0; row < 4; ++row) {
            unsigned grow = (gmb >> (4*row)) & 15u;
            if (grow & 1u) cg5mg += k4[NK-1][row].x;
            if (grow & 2u) cg5mg += k4[NK-1][row].y;
            if (grow & 4u) cg5mg += k4[NK-1][row].z;
            if (grow & 8u) cg5mg += k4[NK-1][row].w;
        }

        // ---- accumulate the 28 sums ----
        float s0 = sig[0];
        acc[0] += s0 * cgm;
        acc[1] += s0 * s0 * cgm;
        acc[2] += cgm;
        acc[3] += cm;
        if (at) {
            acc[4] += cgm;
            acc[5] += cm;
            #pragma unroll
            for (int k = 0; k < NK; ++k) {
                float sk = sig[k+1];
                acc[6 + 3*k] += sk * cgkm[k];
                acc[7 + 3*k] += sk * sk * cm;
                acc[8 + 3*k] += cgkm[k];
            }
        }
        if (a5) {
            acc[24] += cg5mg;
            acc[25] += cgm;
        }
        acc[26] += cg5mg;
        acc[27] += s0 * s0 * (cm - cgm);   // threshold-indep d-term
    }

    // ---- block reduce 28 floats + 2 ints, plain store (no atomics) ----
    #pragma unroll
    for (int i = 0; i < NACC; ++i) {
        #pragma unroll
        for (int off = 32; off; off >>= 1)
            acc[i] += __shfl_down(acc[i], off);
    }
    #pragma unroll
    for (int off = 32; off; off >>= 1) {
        posA += __shfl_down(posA, off);
        negA += __shfl_down(negA, off);
    }
    __shared__ float red[4][NACC];
    __shared__ int sp[4], sn[4];
    int wid = t >> 6, lane = t & 63;
    if (lane == 0) {
        #pragma unroll
        for (int i = 0; i < NACC; ++i) red[wid][i] = acc[i];
        sp[wid] = posA; sn[wid] = negA;
    }
    __syncthreads();
    if (t < NACC)
        pf[bid*32 + t] = red[0][t] + red[1][t] + red[2][t] + red[3][t];
    if (t == 0) {
        pi[2*bid]   = sp[0]+sp[1]+sp[2]+sp[3];
        pi[2*bid+1] = sn[0]+sn[1]+sn[2]+sn[3];
    }
}

// Block-wide (1024 thr) weighted descending select over LDS histogram.
// (general path only — never taken for the benchmark distribution)
template<int NBINS>
__device__ __forceinline__ int bsel(int* __restrict__ lh, int* __restrict__ ws16,
                                    int* __restrict__ wsuf, int* __restrict__ res,
                                    int k, int& krem)
{
    constexpr int CH = NBINS / 1024;
    int t = threadIdx.x, wid = t >> 6, lane = t & 63;
    __syncthreads();
    int c = 0;
    #pragma unroll
    for (int j = 0; j < CH; ++j) c += lh[t*CH + j];
    int s = c;
    #pragma unroll
    for (int off = 1; off < 64; off <<= 1) {
        int v = __shfl_down(s, off);
        if (lane + off < 64) s += v;
    }
    if (lane == 0) ws16[wid] = s;
    __syncthreads();
    if (t < 16) {
        int sum = 0;
        for (int j = t; j < 16; ++j) sum += ws16[j];
        wsuf[t] = sum;
    }
    if (t == 0) { wsuf[16] = 0; res[0] = 0; res[1] = k; }
    __syncthreads();
    int G = s + wsuf[wid + 1];
    int above = G - c;
    if (G >= k && above < k) {
        int cum = above;
        for (int u = t*CH + CH - 1; u >= t*CH; --u) {
            cum += lh[u];
            if (cum >= k) { res[0] = u; res[1] = k - (cum - lh[u]); break; }
        }
    }
    __syncthreads();
    int bin = res[0]; krem = res[1];
    __syncthreads();
    return bin;
}

// ---------- B: threshold + per-batch finalize ----------
__global__ __launch_bounds__(1024) void psel_B(
    const float* __restrict__ maps, const unsigned* __restrict__ bitsbuf,
    const float* __restrict__ pf, const int* __restrict__ pi,
    float* __restrict__ metrics)
{
    __shared__ float fin[NACC];
    __shared__ int ipn[2];
    __shared__ float thrT_sh;
    int b = blockIdx.x, t = threadIdx.x;

    // ---- wave-0 reduce of pf/pi (50 rows per batch) ----
    if (t < 64) {
        float loc[NACC];
        #pragma unroll
        for (int j = 0; j < NACC; ++j) loc[j] = 0.f;
        int p = 0, n = 0;
        if (t < CHUNKS_PER_B) {
            const float* row = pf + (size_t)(b*CHUNKS_PER_B + t) * 32;
            #pragma unroll
            for (int j = 0; j < NACC; ++j) loc[j] = row[j];
            p = pi[(b*CHUNKS_PER_B + t)*2];
            n = pi[(b*CHUNKS_PER_B + t)*2 + 1];
        }
        #pragma unroll
        for (int j = 0; j < NACC; ++j) {
            #pragma unroll
            for (int off = 32; off; off >>= 1)
                loc[j] += __shfl_down(loc[j], off);
        }
        #pragma unroll
        for (int off = 32; off; off >>= 1) {
            p += __shfl_down(p, off);
            n += __shfl_down(n, off);
        }
        if (t == 0) {
            #pragma unroll
            for (int j = 0; j < NACC; ++j) fin[j] = loc[j];
            ipn[0] = p; ipn[1] = n;
        }
    }
    __syncthreads();
    int pos = ipn[0], negT = ipn[1];
    long long nn = (long long)pos * 3; if (nn > negT) nn = negT;
    int k = (int)nn;

    if (pos == 0 || k == 0 || k == negT) {
        // trivial: every pixel selected (or fallback sel=m) -> d-term already in fin[27]
        if (t == 0) thrT_sh = fin[27];
    } else {
        // ---- general weighted radix select + masked d-term re-scan ----
        __shared__ unsigned wpack[NQ4];
        __shared__ int lh[2048];
        __shared__ int ws16[16], wsuf[17], res[2];
        __shared__ float s16[16];
        const float4* mp4 = reinterpret_cast<const float4*>(maps + (size_t)b * NC * NCOARSE);
        const uint4*  bb4 = reinterpret_cast<const uint4*>(bitsbuf + (size_t)b * NCOARSE);
        int wid = t >> 6, lane = t & 63;

        for (int j = t; j < 2048; j += 1024) lh[j] = 0;
        __syncthreads();
        for (int i4 = t; i4 < NQ4; i4 += 1024) {
            float4 m4 = mp4[i4];
            uint4  b4 = bb4[i4];
            float    mv[4] = {m4.x, m4.y, m4.z, m4.w};
            unsigned bv[4] = {b4.x, b4.y, b4.z, b4.w};
            unsigned pk = 0;
            #pragma unroll
            for (int j = 0; j < 4; ++j) {
                int w = 16 - __popc(bv[j] & 0xFFFFu);
                pk |= (unsigned)w << (8*j);
                if (w) atomicAdd(&lh[score_key(mv[j]) >> 21], w);
            }
            wpack[i4] = pk;
        }
        int v = bsel<2048>(lh, ws16, wsuf, res, k, k);
        unsigned prefix = (unsigned)v;

        for (int j = t; j < 2048; j += 1024) lh[j] = 0;
        __syncthreads();
        for (int i4 = t; i4 < NQ4; i4 += 1024) {
            float4 m4 = mp4[i4];
            unsigned pk = wpack[i4];
            float mv[4] = {m4.x, m4.y, m4.z, m4.w};
            #pragma unroll
            for (int j = 0; j < 4; ++j) {
                int w = (pk >> (8*j)) & 255;
                if (w) {
                    unsigned key = score_key(mv[j]);
                    if ((key >> 21) == prefix) atomicAdd(&lh[(key >> 10) & 2047u], w);
                }
            }
        }
        v = bsel<2048>(lh, ws16, wsuf, res, k, k);
        prefix = (prefix << 11) | (unsigned)v;

        for (int j = t; j < 1024; j += 1024) lh[j] = 0;
        __syncthreads();
        for (int i4 = t; i4 < NQ4; i4 += 1024) {
            float4 m4 = mp4[i4];
            unsigned pk = wpack[i4];
            float mv[4] = {m4.x, m4.y, m4.z, m4.w};
            #pragma unroll
            for (int j = 0; j < 4; ++j) {
                int w = (pk >> (8*j)) & 255;
                if (w) {
                    unsigned key = score_key(mv[j]);
                    if ((key >> 10) == prefix) atomicAdd(&lh[key & 1023u], w);
                }
            }
        }
        v = bsel<1024>(lh, ws16, wsuf, res, k, k);
        unsigned thrkey = (prefix << 10) | (unsigned)v;

        float ssum = 0.f;
        for (int i4 = t; i4 < NQ4; i4 += 1024) {
            float4 m4 = mp4[i4];
            uint4  b4 = bb4[i4];
            float    mv[4] = {m4.x, m4.y, m4.z, m4.w};
            unsigned bv[4] = {b4.x, b4.y, b4.z, b4.w};
            #pragma unroll
            for (int j = 0; j < 4; ++j) {
                unsigned w = bv[j];
                float d = (float)(__popc(w >> 16) - __popc(w & (w >> 16) & 0xFFFFu));
                if (d > 0.f && score_key(mv[j]) >= thrkey) {
                    float s = 1.0f / (1.0f + expf(-mv[j]));
                    ssum += s * s * d;
                }
            }
        }
        #pragma unroll
        for (int off = 32; off; off >>= 1) ssum += __shfl_down(ssum, off);
        if (lane == 0) s16[wid] = ssum;
        __syncthreads();
        if (t == 0) {
            float tt = 0.f;
            for (int j = 0; j < 16; ++j) tt += s16[j];
            thrT_sh = tt;
        }
    }
    __syncthreads();

    // ---- per-batch algebra ----
    if (t == 0) {
        const float* a = fin;
        float At = a[0], Bt = a[1] + thrT_sh, Ct = a[2], Sm = a[3], Satgm = a[4], Satm = a[5];
        float lt = 1.f - 2.f*At / (Bt + Ct + 2.f*EPSF);
        float n11 = Satgm;
        float u1 = Satm + Ct - Satgm;
        float i0 = Sm - u1;
        float u0 = Sm - n11;
        float itx = 0.5f * (i0/(u0 + EPSF) + n11/(u1 + EPSF));
        float lks = 0.f;
        #pragma unroll
        for (int kk = 0; kk < NK; ++kk) {
            float Ak = a[6+3*kk], Bk = a[7+3*kk], Ck = a[8+3*kk];
            lks += 1.f - 2.f*Ak / (Bk + Ck + 2.f*EPSF);
        }
        float lk = lks / (float)NK;
        float m11 = a[24], Sa5gm = a[25], Sg5 = a[26];
        float ku1 = Sa5gm + Sg5 - m11;
        float ki0 = Ct - ku1;
        float ku0 = Ct - m11;
        float ik = 0.5f * (ki0/(ku0 + EPSF) + m11/(ku1 + EPSF));
        float l = 0.7f*lt + 0.3f*lk;
        metrics[b*8 + 0] = l;
        metrics[b*8 + 1] = lt;
        metrics[b*8 + 2] = lk;
        metrics[b*8 + 3] = itx;
        metrics[b*8 + 4] = ik;
    }
}

// ---------- D: sum 16x5 metrics ----------
__global__ __launch_bounds__(64) void psel_D(
    const float* __restrict__ metrics, float* __restrict__ out)
{
    int t = threadIdx.x;
    float v[5] = {0.f, 0.f, 0.f, 0.f, 0.f};
    if (t < NB) {
        #pragma unroll
        for (int j = 0; j < 5; ++j) v[j] = metrics[t*8 + j];
    }
    #pragma unroll
    for (int off = 8; off; off >>= 1) {
        #pragma unroll
        for (int j = 0; j < 5; ++j) v[j] += __shfl_down(v[j], off);
    }
    if (t == 0) {
        #pragma unroll
        for (int j = 0; j < 5; ++j) out[j] = v[j];
    }
}

extern "C" void kernel_launch(void* const* d_in, const int* in_sizes, int n_in,
                              void* d_out, int out_size, void* d_ws, size_t ws_size,
                              hipStream_t stream) {
    const float* maps = (const float*)d_in[0];
    const float* gt   = (const float*)d_in[1];
    const float* gk   = (const float*)d_in[2];
    const float* tm   = (const float*)d_in[3];
    float* out = (float*)d_out;
    char* ws = (char*)d_ws;
    float*    pf      = (float*)ws;
    int*      pi      = (int*)(ws + WS_PI);
    float*    metrics = (float*)(ws + WS_MET);
    unsigned* bits    = (unsigned*)(ws + WS_BITS);

    psel_K1<<<KBLOCKS, 256, 0, stream>>>(maps, gt, gk, tm, bits, pf, pi);
    psel_B <<<NB, 1024, 0, stream>>>(maps, bits, pf, pi, metrics);
    psel_D <<<1, 64, 0, stream>>>(metrics, out);
}